// Round 1
// baseline (181.967 us; speedup 1.0000x reference)
//
#include <hip/hip_runtime.h>
#include <cmath>

// ---------------------------------------------------------------------------
// Reference structure:
//   part = conn(sqrtw(plot3))            @128
//   part = conn(merge(part, plot2))      @256
//   part = conn(merge(part, plot1))      @512
//   out  = conn(merge(part, plot0))[:3]  @1024
// merge: pw = part.w*pp (part nearest-upsampled 2x), qw = sqrt(plot.w)
//        clr = (pw*pc + qw*qc)/(pw+qw);  w' = log1p(pw+qw)
// conn:  16 neighbor pairs, f = 1+elu(2*sum(sel channels)), weight ws*f1*f2,
//        out[c] = (center[c] + sum_k f1f2*(c1[c]w1 + c2[c]w2)) / (1 + sum_k ws*f1*f2)
//        out[6] gets merged_k[6] = ws  ->  contribution wk*ws.
//        Out-of-bounds neighbors are 1.0 in ALL channels.
// ---------------------------------------------------------------------------

__device__ __forceinline__ float one_plus_elu(float x) {
    // 1 + elu(x) ; elu(x) = x>0 ? x : expm1(x)
    return x > 0.0f ? 1.0f + x : expf(x);
}

__global__ void init3_kernel(const float* __restrict__ plot, float* __restrict__ X, int n) {
    int idx = blockIdx.x * blockDim.x + threadIdx.x;
    if (idx >= n) return;
    const float* q = plot + (size_t)idx * 7;
    float* o = X + (size_t)idx * 7;
#pragma unroll
    for (int c = 0; c < 6; ++c) o[c] = q[c];
    o[6] = sqrtf(q[6]);
}

__global__ void merge_kernel(const float* __restrict__ part,  // (H/2, W/2, 7)
                             const float* __restrict__ plot,  // (H, W, 7)
                             float* __restrict__ X,           // (H, W, 7)
                             int H, int W,
                             const float* __restrict__ pp_ptr) {
    int j = blockIdx.x * blockDim.x + threadIdx.x;
    int i = blockIdx.y * blockDim.y + threadIdx.y;
    if (i >= H || j >= W) return;
    float pp = pp_ptr[0];
    int Wh = W >> 1;
    const float* P = part + ((size_t)(i >> 1) * Wh + (j >> 1)) * 7;
    const float* Q = plot + ((size_t)i * W + j) * 7;
    float pw = P[6] * pp;
    float qw = sqrtf(Q[6]);
    float ws = pw + qw;
    float inv = 1.0f / ws;
    float* o = X + ((size_t)i * W + j) * 7;
#pragma unroll
    for (int c = 0; c < 6; ++c) o[c] = (P[c] * pw + Q[c] * qw) * inv;
    o[6] = log1pf(ws);
}

// Pair tables: n[a][b] = fetch(i + a - 1, j + b - 1), a = J (row), b = I (col).
// Mask bit t (t=0..3) selects channel t+2 for the elu-gate sum.
template <int OUTCH>
__global__ void conn_kernel(const float* __restrict__ X, float* __restrict__ Y, int H, int W) {
    constexpr int A1[16] = {0,2,0,1,0,0,0,0,0,1,0,1,0,0,1,2};
    constexpr int B1[16] = {0,0,1,0,1,1,0,2,2,0,0,2,1,1,0,1};
    constexpr int M1[16] = {5,9,1,4,6,10,10,6,6,10,10,6,5,9,5,9};
    constexpr int A2[16] = {2,0,2,1,2,2,2,2,1,2,1,2,1,0,2,1};
    constexpr int B2[16] = {2,2,1,2,0,2,1,1,0,2,2,0,2,1,1,2};
    constexpr int M2[16] = {10,6,2,8,9,5,5,9,9,5,5,9,10,6,10,6};

    int j = blockIdx.x * blockDim.x + threadIdx.x;
    int i = blockIdx.y * blockDim.y + threadIdx.y;
    if (i >= H || j >= W) return;

    float nb[3][3][7];
#pragma unroll
    for (int a = 0; a < 3; ++a) {
        int ii = i + a - 1;
#pragma unroll
        for (int b = 0; b < 3; ++b) {
            int jj = j + b - 1;
            bool ok = (ii >= 0) & (ii < H) & (jj >= 0) & (jj < W);
            const float* p = X + ((size_t)(ok ? ii : 0) * W + (ok ? jj : 0)) * 7;
#pragma unroll
            for (int c = 0; c < 7; ++c) nb[a][b][c] = ok ? p[c] : 1.0f;
        }
    }

    float acc[7];
    float wsum = 1.0f;
#pragma unroll
    for (int c = 0; c < 7; ++c) acc[c] = nb[1][1][c];

#pragma unroll
    for (int k = 0; k < 16; ++k) {
        const float* p1 = nb[A1[k]][B1[k]];
        const float* p2 = nb[A2[k]][B2[k]];
        float s1 = 0.0f, s2 = 0.0f;
#pragma unroll
        for (int t = 0; t < 4; ++t) {
            if (M1[k] & (1 << t)) s1 += p1[t + 2];
            if (M2[k] & (1 << t)) s2 += p2[t + 2];
        }
        float f1 = one_plus_elu(2.0f * s1);
        float f2 = one_plus_elu(2.0f * s2);
        float g  = f1 * f2;
        float w1 = p1[6], w2 = p2[6];
        float wsp = w1 + w2;
        float wk  = wsp * g;
        wsum += wk;
#pragma unroll
        for (int c = 0; c < 6; ++c) acc[c] += g * (p1[c] * w1 + p2[c] * w2);
        acc[6] += wk * wsp;
    }

    float inv = 1.0f / wsum;
    float* o = Y + ((size_t)i * W + j) * OUTCH;
#pragma unroll
    for (int c = 0; c < OUTCH; ++c) o[c] = acc[c] * inv;
}

extern "C" void kernel_launch(void* const* d_in, const int* in_sizes, int n_in,
                              void* d_out, int out_size, void* d_ws, size_t ws_size,
                              hipStream_t stream) {
    const float* plot0 = (const float*)d_in[0];  // 1024x1024x7
    const float* plot1 = (const float*)d_in[1];  // 512x512x7
    const float* plot2 = (const float*)d_in[2];  // 256x256x7
    const float* plot3 = (const float*)d_in[3];  // 128x128x7
    const float* pp    = (const float*)d_in[5];  // scalar
    float* out = (float*)d_out;                  // 1024x1024x3

    float* bufX = (float*)d_ws;                         // up to 1024^2 * 7
    float* bufY = bufX + (size_t)1024 * 1024 * 7;       // up to 512^2 * 7

    dim3 blk(64, 4);

    // level 3 @128
    init3_kernel<<<(128 * 128 + 255) / 256, 256, 0, stream>>>(plot3, bufX, 128 * 128);
    conn_kernel<7><<<dim3(2, 32), blk, 0, stream>>>(bufX, bufY, 128, 128);
    // level 2 @256
    merge_kernel<<<dim3(4, 64), blk, 0, stream>>>(bufY, plot2, bufX, 256, 256, pp);
    conn_kernel<7><<<dim3(4, 64), blk, 0, stream>>>(bufX, bufY, 256, 256);
    // level 1 @512
    merge_kernel<<<dim3(8, 128), blk, 0, stream>>>(bufY, plot1, bufX, 512, 512, pp);
    conn_kernel<7><<<dim3(8, 128), blk, 0, stream>>>(bufX, bufY, 512, 512);
    // level 0 @1024
    merge_kernel<<<dim3(16, 256), blk, 0, stream>>>(bufY, plot0, bufX, 1024, 1024, pp);
    conn_kernel<3><<<dim3(16, 256), blk, 0, stream>>>(bufX, out, 1024, 1024);
}

// Round 2
// 57.812 us; speedup vs baseline: 3.1475x; 3.1475x over previous
//
#include <hip/hip_runtime.h>
#include <cmath>

// Pipeline:
//   part = conn(init(plot3))            @128    (MODE 0)
//   part = conn(merge(part, plot2))     @256    (MODE 1)
//   part = conn(merge(part, plot1))     @512    (MODE 1)
//   out  = conn(merge(part, plot0))[:3] @1024   (MODE 1, OUTCH 3)
// merge: pw = part.w*pp (nearest-upsample 2x), qw = sqrt(plot.w)
//        clr = (pw*pc + qw*qc)/(pw+qw);  w' = log1p(pw+qw)
// conn:  16 neighbor pairs, f = 1+elu(2*sum(sel channels)), weight ws*f1*f2,
//        out[c] = (center[c] + sum_k f1f2*(c1[c]w1+c2[c]w2)) / (1 + sum_k ws*f1*f2)
//        acc[6] += wk*ws.  OOB neighbors = 1.0 in ALL channels.
// Fused: block stages 18x18x7 MERGED tile in LDS, conn reads LDS only.

__device__ __forceinline__ float one_plus_elu(float x) {
    return x > 0.0f ? 1.0f + x : expf(x);
}

template <int MODE, int OUTCH>
__global__ __launch_bounds__(256) void fused_kernel(
    const float* __restrict__ part,   // (H/2, W/2, 7)  [MODE 1 only]
    const float* __restrict__ plot,   // (H, W, 7)
    float* __restrict__ out,          // (H, W, OUTCH)
    int H, int W,
    const float* __restrict__ pp_ptr)
{
    __shared__ float lds[18][18][7];  // 9072 B

    const int tx = threadIdx.x, ty = threadIdx.y;
    const int tid = ty * 16 + tx;
    const int bx = blockIdx.x * 16, by = blockIdx.y * 16;
    const int Wh = W >> 1;
    const float pp = (MODE == 1) ? pp_ptr[0] : 0.0f;

    // ---- stage merged halo tile ----
    for (int cell = tid; cell < 324; cell += 256) {
        int ci = cell / 18;
        int cj = cell - ci * 18;
        int gi = by + ci - 1;
        int gj = bx + cj - 1;
        float v[7];
        if (gi >= 0 && gi < H && gj >= 0 && gj < W) {
            const float* Q = plot + ((size_t)gi * W + gj) * 7;
            if (MODE == 0) {
#pragma unroll
                for (int c = 0; c < 6; ++c) v[c] = Q[c];
                v[6] = sqrtf(Q[6]);
            } else {
                const float* P = part + ((size_t)(gi >> 1) * Wh + (gj >> 1)) * 7;
                float pw = P[6] * pp;
                float qw = sqrtf(Q[6]);
                float ws = pw + qw;
                float inv = 1.0f / ws;
#pragma unroll
                for (int c = 0; c < 6; ++c) v[c] = (P[c] * pw + Q[c] * qw) * inv;
                v[6] = log1pf(ws);
            }
        } else {
#pragma unroll
            for (int c = 0; c < 7; ++c) v[c] = 1.0f;
        }
#pragma unroll
        for (int c = 0; c < 7; ++c) lds[ci][cj][c] = v[c];
    }
    __syncthreads();

    // ---- conn from LDS ----
    constexpr int A1[16] = {0,2,0,1,0,0,0,0,0,1,0,1,0,0,1,2};
    constexpr int B1[16] = {0,0,1,0,1,1,0,2,2,0,0,2,1,1,0,1};
    constexpr int M1[16] = {5,9,1,4,6,10,10,6,6,10,10,6,5,9,5,9};
    constexpr int A2[16] = {2,0,2,1,2,2,2,2,1,2,1,2,1,0,2,1};
    constexpr int B2[16] = {2,2,1,2,0,2,1,1,0,2,2,0,2,1,1,2};
    constexpr int M2[16] = {10,6,2,8,9,5,5,9,9,5,5,9,10,6,10,6};

    float nb[3][3][7];
#pragma unroll
    for (int a = 0; a < 3; ++a)
#pragma unroll
        for (int b = 0; b < 3; ++b)
#pragma unroll
            for (int c = 0; c < 7; ++c) nb[a][b][c] = lds[ty + a][tx + b][c];

    float acc[7];
    float wsum = 1.0f;
#pragma unroll
    for (int c = 0; c < 7; ++c) acc[c] = nb[1][1][c];

#pragma unroll
    for (int k = 0; k < 16; ++k) {
        const float* p1 = nb[A1[k]][B1[k]];
        const float* p2 = nb[A2[k]][B2[k]];
        float s1 = 0.0f, s2 = 0.0f;
#pragma unroll
        for (int t = 0; t < 4; ++t) {
            if (M1[k] & (1 << t)) s1 += p1[t + 2];
            if (M2[k] & (1 << t)) s2 += p2[t + 2];
        }
        float f1 = one_plus_elu(2.0f * s1);
        float f2 = one_plus_elu(2.0f * s2);
        float g  = f1 * f2;
        float w1 = p1[6], w2 = p2[6];
        float wsp = w1 + w2;
        float wk  = wsp * g;
        wsum += wk;
#pragma unroll
        for (int c = 0; c < 6; ++c) acc[c] += g * (p1[c] * w1 + p2[c] * w2);
        acc[6] += wk * wsp;
    }

    float inv = 1.0f / wsum;
    const int gi = by + ty, gj = bx + tx;
    float* o = out + ((size_t)gi * W + gj) * OUTCH;
#pragma unroll
    for (int c = 0; c < OUTCH; ++c) o[c] = acc[c] * inv;
}

extern "C" void kernel_launch(void* const* d_in, const int* in_sizes, int n_in,
                              void* d_out, int out_size, void* d_ws, size_t ws_size,
                              hipStream_t stream) {
    const float* plot0 = (const float*)d_in[0];  // 1024x1024x7
    const float* plot1 = (const float*)d_in[1];  // 512x512x7
    const float* plot2 = (const float*)d_in[2];  // 256x256x7
    const float* plot3 = (const float*)d_in[3];  // 128x128x7
    const float* pp    = (const float*)d_in[5];  // scalar
    float* out = (float*)d_out;                  // 1024x1024x3

    float* bufA = (float*)d_ws;                       // up to 512^2 * 7
    float* bufB = bufA + (size_t)512 * 512 * 7;       // up to 512^2 * 7

    dim3 blk(16, 16);

    // level 3 @128 (init + conn)
    fused_kernel<0, 7><<<dim3(8, 8),   blk, 0, stream>>>(nullptr, plot3, bufA, 128, 128, pp);
    // level 2 @256
    fused_kernel<1, 7><<<dim3(16, 16), blk, 0, stream>>>(bufA, plot2, bufB, 256, 256, pp);
    // level 1 @512
    fused_kernel<1, 7><<<dim3(32, 32), blk, 0, stream>>>(bufB, plot1, bufA, 512, 512, pp);
    // level 0 @1024
    fused_kernel<1, 3><<<dim3(64, 64), blk, 0, stream>>>(bufA, plot0, out, 1024, 1024, pp);
}

// Round 3
// 45.697 us; speedup vs baseline: 3.9820x; 1.2651x over previous
//
#include <hip/hip_runtime.h>
#include <cmath>

// Pipeline (fused merge+conn per level):
//   part = conn(init(plot3))            @128    (MODE 0)  -> bufA (stride 8)
//   part = conn(merge(part, plot2))     @256    (MODE 1)  -> bufB (stride 8)
//   part = conn(merge(part, plot1))     @512    (MODE 1)  -> bufA (stride 8)
//   out  = conn(merge(part, plot0))[:3] @1024   (MODE 1)  -> d_out (stride 3)
// merge: pw = part.w*pp (nearest-up 2x), qw = sqrt(plot.w)
//        clr = (pw*pc + qw*qc)/(pw+qw);  w' = log1p(pw+qw)
// conn:  16 pairs, f = 1+elu(2*sum(sel ch2..5)), g=f1*f2, wsp=w1+w2
//        acc[0..5] += g*(c1*w1+c2*w2); acc[6] += g*wsp^2; wsum += g*wsp
//        out = acc/wsum. OOB neighbors = 1.0 in ALL channels.
// LDS: two float4 planes (A=ch0..3, B=ch4,ch5,w,pad) -> conflict-free b128.

__device__ __forceinline__ float one_plus_elu(float x) {
    return x > 0.0f ? 1.0f + x : __expf(x);
}

// PSTRIDE: channel stride of incoming part buffer (8 = our padded layout)
// OUTCH: 7 -> write 8-stride padded part; 3 -> write 3-stride final output
template <int MODE, int OUTCH>
__global__ __launch_bounds__(256) void fused_kernel(
    const float* __restrict__ part,   // (H/2, W/2, 8)  [MODE 1 only]
    const float* __restrict__ plot,   // (H, W, 7)
    float* __restrict__ out,          // (H, W, OUTCH==7 ? 8 : 3)
    int H, int W,
    const float* __restrict__ pp_ptr)
{
    __shared__ float4 ldsA[18][18];   // ch0..3
    __shared__ float4 ldsB[18][18];   // ch4, ch5, w, pad

    const int tx = threadIdx.x, ty = threadIdx.y;
    const int tid = ty * 16 + tx;
    const int bx = blockIdx.x * 16, by = blockIdx.y * 16;
    const int Wh = W >> 1;
    const float pp = (MODE == 1) ? pp_ptr[0] : 0.0f;

    // ---- stage merged halo tile (18x18) ----
    for (int cell = tid; cell < 324; cell += 256) {
        int ci = cell / 18;
        int cj = cell - ci * 18;
        int gi = by + ci - 1;
        int gj = bx + cj - 1;
        float4 va, vb;
        if (gi >= 0 && gi < H && gj >= 0 && gj < W) {
            const float* Q = plot + ((size_t)gi * W + gj) * 7;
            if (MODE == 0) {
                va = make_float4(Q[0], Q[1], Q[2], Q[3]);
                vb = make_float4(Q[4], Q[5], __builtin_amdgcn_sqrtf(Q[6]), 0.0f);
            } else {
                const float4* P4 = (const float4*)(part + ((size_t)(gi >> 1) * Wh + (gj >> 1)) * 8);
                float4 pa = P4[0];
                float4 pb = P4[1];
                float pw = pb.z * pp;
                float qw = __builtin_amdgcn_sqrtf(Q[6]);
                float ws = pw + qw;
                float inv = __builtin_amdgcn_rcpf(ws);
                va.x = (pa.x * pw + Q[0] * qw) * inv;
                va.y = (pa.y * pw + Q[1] * qw) * inv;
                va.z = (pa.z * pw + Q[2] * qw) * inv;
                va.w = (pa.w * pw + Q[3] * qw) * inv;
                vb.x = (pb.x * pw + Q[4] * qw) * inv;
                vb.y = (pb.y * pw + Q[5] * qw) * inv;
                vb.z = __logf(1.0f + ws);
                vb.w = 0.0f;
            }
        } else {
            va = make_float4(1.0f, 1.0f, 1.0f, 1.0f);
            vb = make_float4(1.0f, 1.0f, 1.0f, 0.0f);
        }
        ldsA[ci][cj] = va;
        ldsB[ci][cj] = vb;
    }
    __syncthreads();

    // ---- conn from LDS: explicit register window ----
    float4 a[3][3], b[3][3];
#pragma unroll
    for (int r = 0; r < 3; ++r)
#pragma unroll
        for (int cidx = 0; cidx < 3; ++cidx) {
            a[r][cidx] = ldsA[ty + r][tx + cidx];
            b[r][cidx] = ldsB[ty + r][tx + cidx];
        }

    constexpr int A1[16] = {0,2,0,1,0,0,0,0,0,1,0,1,0,0,1,2};
    constexpr int B1[16] = {0,0,1,0,1,1,0,2,2,0,0,2,1,1,0,1};
    constexpr int M1[16] = {5,9,1,4,6,10,10,6,6,10,10,6,5,9,5,9};
    constexpr int A2[16] = {2,0,2,1,2,2,2,2,1,2,1,2,1,0,2,1};
    constexpr int B2[16] = {2,2,1,2,0,2,1,1,0,2,2,0,2,1,1,2};
    constexpr int M2[16] = {10,6,2,8,9,5,5,9,9,5,5,9,10,6,10,6};

    float4 accA = a[1][1];
    float acc4 = b[1][1].x, acc5 = b[1][1].y, acc6 = b[1][1].z;
    float wsum = 1.0f;

#pragma unroll
    for (int k = 0; k < 16; ++k) {
        const float4 a1 = a[A1[k]][B1[k]], b1 = b[A1[k]][B1[k]];
        const float4 a2 = a[A2[k]][B2[k]], b2 = b[A2[k]][B2[k]];
        float s1 = 0.0f, s2 = 0.0f;
        if (M1[k] & 1) s1 += a1.z;
        if (M1[k] & 2) s1 += a1.w;
        if (M1[k] & 4) s1 += b1.x;
        if (M1[k] & 8) s1 += b1.y;
        if (M2[k] & 1) s2 += a2.z;
        if (M2[k] & 2) s2 += a2.w;
        if (M2[k] & 4) s2 += b2.x;
        if (M2[k] & 8) s2 += b2.y;
        float f1 = one_plus_elu(2.0f * s1);
        float f2 = one_plus_elu(2.0f * s2);
        float g  = f1 * f2;
        float w1 = b1.z, w2 = b2.z;
        float wsp = w1 + w2;
        float gw1 = g * w1, gw2 = g * w2;
        accA.x += gw1 * a1.x + gw2 * a2.x;
        accA.y += gw1 * a1.y + gw2 * a2.y;
        accA.z += gw1 * a1.z + gw2 * a2.z;
        accA.w += gw1 * a1.w + gw2 * a2.w;
        acc4   += gw1 * b1.x + gw2 * b2.x;
        acc5   += gw1 * b1.y + gw2 * b2.y;
        float gws = g * wsp;
        wsum += gws;
        acc6 += gws * wsp;
    }

    float inv = __builtin_amdgcn_rcpf(wsum);
    const int gi = by + ty, gj = bx + tx;
    if (OUTCH == 7) {
        float4* o4 = (float4*)(out + ((size_t)gi * W + gj) * 8);
        o4[0] = make_float4(accA.x * inv, accA.y * inv, accA.z * inv, accA.w * inv);
        o4[1] = make_float4(acc4 * inv, acc5 * inv, acc6 * inv, 0.0f);
    } else {
        float* o = out + ((size_t)gi * W + gj) * 3;
        o[0] = accA.x * inv;
        o[1] = accA.y * inv;
        o[2] = accA.z * inv;
    }
}

extern "C" void kernel_launch(void* const* d_in, const int* in_sizes, int n_in,
                              void* d_out, int out_size, void* d_ws, size_t ws_size,
                              hipStream_t stream) {
    const float* plot0 = (const float*)d_in[0];  // 1024x1024x7
    const float* plot1 = (const float*)d_in[1];  // 512x512x7
    const float* plot2 = (const float*)d_in[2];  // 256x256x7
    const float* plot3 = (const float*)d_in[3];  // 128x128x7
    const float* pp    = (const float*)d_in[5];  // scalar
    float* out = (float*)d_out;                  // 1024x1024x3

    float* bufA = (float*)d_ws;                       // up to 512^2 * 8
    float* bufB = bufA + (size_t)512 * 512 * 8;       // up to 256^2 * 8

    dim3 blk(16, 16);

    // level 3 @128 (init + conn)
    fused_kernel<0, 7><<<dim3(8, 8),   blk, 0, stream>>>(nullptr, plot3, bufA, 128, 128, pp);
    // level 2 @256
    fused_kernel<1, 7><<<dim3(16, 16), blk, 0, stream>>>(bufA, plot2, bufB, 256, 256, pp);
    // level 1 @512
    fused_kernel<1, 7><<<dim3(32, 32), blk, 0, stream>>>(bufB, plot1, bufA, 512, 512, pp);
    // level 0 @1024
    fused_kernel<1, 3><<<dim3(64, 64), blk, 0, stream>>>(bufA, plot0, out, 1024, 1024, pp);
}

// Round 4
// 38.239 us; speedup vs baseline: 4.7587x; 1.1950x over previous
//
#include <hip/hip_runtime.h>
#include <cmath>

// Pipeline (fused merge+conn per level):
//   part = conn(init(plot3))            @128    (MODE 0)  -> bufA (stride 8)
//   part = conn(merge(part, plot2))     @256    (MODE 1)  -> bufB (stride 8)
//   part = conn(merge(part, plot1))     @512    (MODE 1)  -> bufA (stride 8)
//   out  = conn(merge(part, plot0))[:3] @1024   (MODE 1)  -> d_out (stride 3)
//
// conn restructured (premultiplied + grouped):
//   staging per pixel: raw c0..c5, w  ->  P = c*w, and 8 elu-gates
//     f[m] = 1+elu(2*s_m), s: {c2, c3, c4, c5, c2+c4, c3+c4, c2+c5, c3+c5}
//   conn per pixel: g_k = f[cell1][m1]*f[cell2][m2]  (16 pairs)
//     G_cell = sum of g_k over pair slots containing cell
//     acc[c] = center_c + sum_cells G_cell * P_cell[c]
//     wsum   = 1 + sum_cells G_cell * w_cell
//     acc6   = w_center + sum_k g_k*(w1+w2)^2
//   OOB cells: raw c = w = 1 (gates follow from same formula).

typedef float f4a4 __attribute__((ext_vector_type(4))) __attribute__((aligned(4)));

__device__ __forceinline__ float one_plus_elu(float x) {
    return x > 0.0f ? 1.0f + x : __expf(x);
}

template <int MODE, int OUTCH>
__global__ __launch_bounds__(256) void fused_kernel(
    const float* __restrict__ part,   // (H/2, W/2, 8)  [MODE 1 only]
    const float* __restrict__ plot,   // (H, W, 7)
    float* __restrict__ out,          // (H, W, OUTCH==7 ? 8 : 3)
    int H, int W,
    const float* __restrict__ pp_ptr)
{
    __shared__ float4 ldsA[18][18];     // P0..P3 (premultiplied)
    __shared__ float4 ldsB[18][18];     // P4, P5, w, pad
    __shared__ float  ldsW[18][18];     // w (scalar plane, conflict-light)
    __shared__ float  ldsF[8][18][18];  // gates f[m]

    const int tx = threadIdx.x, ty = threadIdx.y;
    const int tid = ty * 16 + tx;
    const int bx = blockIdx.x * 16, by = blockIdx.y * 16;
    const int Wh = W >> 1;
    const float pp = (MODE == 1) ? pp_ptr[0] : 0.0f;

    // ---- stage merged halo tile (18x18): premult colors + gates ----
    for (int cell = tid; cell < 324; cell += 256) {
        int ci = cell / 18;
        int cj = cell - ci * 18;
        int gi = by + ci - 1;
        int gj = bx + cj - 1;
        float c0, c1v, c2, c3, c4, c5, w;
        if (gi >= 0 && gi < H && gj >= 0 && gj < W) {
            const float* Q = plot + ((size_t)gi * W + gj) * 7;
            f4a4 qa = *(const f4a4*)(Q);      // c0 c1 c2 c3
            f4a4 qb = *(const f4a4*)(Q + 3);  // c3 c4 c5 c6
            if (MODE == 0) {
                c0 = qa.x; c1v = qa.y; c2 = qa.z; c3 = qa.w;
                c4 = qb.y; c5 = qb.z;
                w = __builtin_amdgcn_sqrtf(qb.w);
            } else {
                const float4* P4 = (const float4*)(part + ((size_t)(gi >> 1) * Wh + (gj >> 1)) * 8);
                float4 pa = P4[0];
                float4 pb = P4[1];
                float pw = pb.z * pp;
                float qw = __builtin_amdgcn_sqrtf(qb.w);
                float ws = pw + qw;
                float inv = __builtin_amdgcn_rcpf(ws);
                c0  = (pa.x * pw + qa.x * qw) * inv;
                c1v = (pa.y * pw + qa.y * qw) * inv;
                c2  = (pa.z * pw + qa.z * qw) * inv;
                c3  = (pa.w * pw + qa.w * qw) * inv;
                c4  = (pb.x * pw + qb.y * qw) * inv;
                c5  = (pb.y * pw + qb.z * qw) * inv;
                w = __logf(1.0f + ws);
            }
        } else {
            c0 = c1v = c2 = c3 = c4 = c5 = w = 1.0f;
        }
        // gates (masks: m1,m2,m4,m8,m5,m6,m9,m10 -> planes 0..7)
        float f0 = one_plus_elu(2.0f * c2);
        float f1 = one_plus_elu(2.0f * c3);
        float f2 = one_plus_elu(2.0f * c4);
        float f3 = one_plus_elu(2.0f * c5);
        float f4 = one_plus_elu(2.0f * (c2 + c4));
        float f5 = one_plus_elu(2.0f * (c3 + c4));
        float f6 = one_plus_elu(2.0f * (c2 + c5));
        float f7 = one_plus_elu(2.0f * (c3 + c5));
        ldsA[ci][cj] = make_float4(c0 * w, c1v * w, c2 * w, c3 * w);
        ldsB[ci][cj] = make_float4(c4 * w, c5 * w, w, 0.0f);
        ldsW[ci][cj] = w;
        ldsF[0][ci][cj] = f0; ldsF[1][ci][cj] = f1;
        ldsF[2][ci][cj] = f2; ldsF[3][ci][cj] = f3;
        ldsF[4][ci][cj] = f4; ldsF[5][ci][cj] = f5;
        ldsF[6][ci][cj] = f6; ldsF[7][ci][cj] = f7;
    }
    __syncthreads();

    // ---- conn: grouped accumulation ----
    // cells 0..8 = (r,c) row-major; center = 4.
    // pair tables: cell idx + gate plane idx per slot.
    constexpr int C1[16]  = {0,6,1,3,1,1,0,2,2,3,0,5,1,1,3,7};
    constexpr int MI1[16] = {4,6,0,2,5,7,7,5,5,7,7,5,4,6,4,6};
    constexpr int C2[16]  = {8,2,7,5,6,8,7,7,3,8,5,6,5,1,7,5};
    constexpr int MI2[16] = {7,5,1,3,6,4,4,6,6,4,4,6,7,5,7,5};

    float wv[9];
#pragma unroll
    for (int cl = 0; cl < 9; ++cl) wv[cl] = ldsW[ty + cl / 3][tx + cl % 3];

    float G[9] = {0,0,0,0,0,0,0,0,0};
    float wsum = 1.0f;
    float acc6 = wv[4];

#pragma unroll
    for (int k = 0; k < 16; ++k) {
        float fa = ldsF[MI1[k]][ty + C1[k] / 3][tx + C1[k] % 3];
        float fb = ldsF[MI2[k]][ty + C2[k] / 3][tx + C2[k] % 3];
        float gk = fa * fb;
        G[C1[k]] += gk;
        G[C2[k]] += gk;
        float wsp = wv[C1[k]] + wv[C2[k]];
        float gws = gk * wsp;
        wsum += gws;
        acc6 += gws * wsp;
    }

    // center raw colors (recover from premultiplied via rcp(w))
    float4 accA;
    float a4, a5;
    {
        float4 ca = ldsA[ty + 1][tx + 1];
        float4 cb = ldsB[ty + 1][tx + 1];
        float rw = __builtin_amdgcn_rcpf(cb.z);
        accA = make_float4(ca.x * rw, ca.y * rw, ca.z * rw, ca.w * rw);
        a4 = cb.x * rw;
        a5 = cb.y * rw;
    }

#pragma unroll
    for (int cl = 0; cl < 9; ++cl) {
        if (cl == 4) continue;
        float4 pa = ldsA[ty + cl / 3][tx + cl % 3];
        float4 pb = ldsB[ty + cl / 3][tx + cl % 3];
        float Gg = G[cl];
        accA.x += Gg * pa.x;
        accA.y += Gg * pa.y;
        accA.z += Gg * pa.z;
        accA.w += Gg * pa.w;
        a4 += Gg * pb.x;
        a5 += Gg * pb.y;
    }

    float inv = __builtin_amdgcn_rcpf(wsum);
    const int gi = by + ty, gj = bx + tx;
    if (OUTCH == 7) {
        float4* o4 = (float4*)(out + ((size_t)gi * W + gj) * 8);
        o4[0] = make_float4(accA.x * inv, accA.y * inv, accA.z * inv, accA.w * inv);
        o4[1] = make_float4(a4 * inv, a5 * inv, acc6 * inv, 0.0f);
    } else {
        float* o = out + ((size_t)gi * W + gj) * 3;
        o[0] = accA.x * inv;
        o[1] = accA.y * inv;
        o[2] = accA.z * inv;
    }
}

extern "C" void kernel_launch(void* const* d_in, const int* in_sizes, int n_in,
                              void* d_out, int out_size, void* d_ws, size_t ws_size,
                              hipStream_t stream) {
    const float* plot0 = (const float*)d_in[0];  // 1024x1024x7
    const float* plot1 = (const float*)d_in[1];  // 512x512x7
    const float* plot2 = (const float*)d_in[2];  // 256x256x7
    const float* plot3 = (const float*)d_in[3];  // 128x128x7
    const float* pp    = (const float*)d_in[5];  // scalar
    float* out = (float*)d_out;                  // 1024x1024x3

    float* bufA = (float*)d_ws;                       // up to 512^2 * 8
    float* bufB = bufA + (size_t)512 * 512 * 8;       // up to 256^2 * 8

    dim3 blk(16, 16);

    fused_kernel<0, 7><<<dim3(8, 8),   blk, 0, stream>>>(nullptr, plot3, bufA, 128, 128, pp);
    fused_kernel<1, 7><<<dim3(16, 16), blk, 0, stream>>>(bufA, plot2, bufB, 256, 256, pp);
    fused_kernel<1, 7><<<dim3(32, 32), blk, 0, stream>>>(bufB, plot1, bufA, 512, 512, pp);
    fused_kernel<1, 3><<<dim3(64, 64), blk, 0, stream>>>(bufA, plot0, out, 1024, 1024, pp);
}